// Round 2
// baseline (358.468 us; speedup 1.0000x reference)
//
#include <hip/hip_runtime.h>
#include <hip/hip_fp16.h>
#include <hip/hip_cooperative_groups.h>

namespace cg = cooperative_groups;

// Per-point expert-indexed MLP: h = LeakyReLU(h @ W[idx] + b[idx]) x3.
//
// Pipeline (2 dispatches):
//   k_pre (cooperative, nblk blocks):
//     phase A: per-chunk histogram (int4 loads, kept in regs) + fp16 weight prep
//     grid.sync
//     phase B: 16 blocks scan one expert's partials each (block-parallel scan)
//     grid.sync
//     phase C: block 0 wave 0: padded segment offsets (16-lane shfl scan)
//     grid.sync
//     phase D: scatter pid using idx STILL IN REGISTERS (no re-read)
//   k_mlp  : unchanged from R11-verified version (fdot2, MPT=4, spill-contained).
//
// R12: fused hist/scan/scatter into one cooperative kernel. Removes the
// 1-block k_scan dispatch (whole-GPU idle ~8-10us) + 2 dispatch gaps + idx
// re-read. k_mlp codegen untouched.

#define L_EXP 16
#define IN0   7
#define C0    16
#define C1    32
#define C2    16
#define NEG   0.2f
#define BLK   256
#define MPT   4
#define SEGPAD (BLK * MPT)   // 1024
#define CHUNK  1024          // points per pre block
#define NBM    512           // max pre blocks (n <= 524288)

// transposed-packed fp16 weight counts (halves)
#define NW0T 2048            // 16 experts x [16 o][8 c-padded]
#define NW1T 8192            // 16 experts x [32 o][16 c]
#define NW2T 8192            // 16 experts x [16 o][32 c]
#define NWT_TOT (NW0T + NW1T + NW2T)       // 18432
#define PREPBLK (NWT_TOT / BLK)            // 72

// ws layout:
//   int [0..15]            counts per expert
//   int [16..32]           padded seg offsets, [32] = padded total
//   int [64 .. 64+16*NBM)  partial hist -> exclusive block prefixes [e][b]
//   byte 33792             hW0t: 2048 halves (4096 B)   [e][o][c0..7 pad]
//   byte 37888             hW1t: 8192 halves (16384 B)  [e][o][c0..15]
//   byte 54272             hW2t: 8192 halves (16384 B)  [e][o][c0..31]
//   int [18432 .. )        perm: pid per sorted slot (pads: poison, clamped)
#define WS_PART  64
#define WB_W0T   33792
#define WB_W1T   37888
#define WB_W2T   54272
#define WS_PERM  18432

typedef _Float16 h2 __attribute__((ext_vector_type(2)));
union F4H { float4 f4; h2 h[4]; };

__device__ __forceinline__ h2 pk(float a, float b) {
    return __builtin_bit_cast(h2, __builtin_amdgcn_cvt_pkrtz(a, b));
}

__global__ void k_pre(const int* __restrict__ idx, int n, int nblk,
                      int* __restrict__ ws,
                      const float* __restrict__ W0,
                      const float* __restrict__ W1,
                      const float* __restrict__ W2) {
    cg::grid_group grid = cg::this_grid();
    int t = threadIdx.x;
    int b = blockIdx.x;

    __shared__ int bins[L_EXP];
    __shared__ int wsum[4];
    __shared__ int soff[L_EXP];
    __shared__ int lcount[L_EXP];

    // ---- phase A: histogram chunk b (idx kept in registers) + weight prep ----
    if (t < L_EXP) bins[t] = 0;
    __syncthreads();

    int i4 = b * CHUNK + t * 4;
    int4 v = make_int4(-1, -1, -1, -1);
    if (i4 + 3 < n) {
        v = *reinterpret_cast<const int4*>(idx + i4);
        atomicAdd(&bins[v.x & 15], 1);
        atomicAdd(&bins[v.y & 15], 1);
        atomicAdd(&bins[v.z & 15], 1);
        atomicAdd(&bins[v.w & 15], 1);
    } else {
        int q0 = (i4 + 0 < n) ? idx[i4 + 0] : -1;
        int q1 = (i4 + 1 < n) ? idx[i4 + 1] : -1;
        int q2 = (i4 + 2 < n) ? idx[i4 + 2] : -1;
        int q3 = (i4 + 3 < n) ? idx[i4 + 3] : -1;
        v = make_int4(q0, q1, q2, q3);
        if (q0 >= 0) atomicAdd(&bins[q0 & 15], 1);
        if (q1 >= 0) atomicAdd(&bins[q1 & 15], 1);
        if (q2 >= 0) atomicAdd(&bins[q2 & 15], 1);
        if (q3 >= 0) atomicAdd(&bins[q3 & 15], 1);
    }
    __syncthreads();
    if (t < L_EXP) ws[WS_PART + t * NBM + b] = bins[t];

    // weight prep distributed over first PREPBLK block-slots (stride loop: safe
    // for any nblk >= 1)
    {
        __half* hW0 = (__half*)((char*)ws + WB_W0T);
        __half* hW1 = (__half*)((char*)ws + WB_W1T);
        __half* hW2 = (__half*)((char*)ws + WB_W2T);
        for (int kb = b; kb < PREPBLK; kb += nblk) {
            int k = kb * BLK + t;
            if (k < NW0T) {
                int e = k >> 7, r = k & 127, o = r >> 3, c = r & 7;
                float w = (c < IN0) ? W0[e * (IN0 * C0) + c * C0 + o] : 0.0f;
                hW0[k] = __float2half(w);
            } else if (k < NW0T + NW1T) {
                int k2 = k - NW0T;
                int e = k2 >> 9, r = k2 & 511, o = r >> 4, c = r & 15;
                hW1[k2] = __float2half(W1[e * (C0 * C1) + c * C1 + o]);
            } else {
                int k2 = k - NW0T - NW1T;
                int e = k2 >> 9, r = k2 & 511, o = r >> 5, c = r & 31;
                hW2[k2] = __float2half(W2[e * (C1 * C2) + c * C2 + o]);
            }
        }
    }
    __threadfence();
    grid.sync();

    // ---- phase B: blocks 0..15 scan expert b's partials (block-parallel) ----
    if (b < L_EXP) {
        int e = b;
        int wid = t >> 6, lane = t & 63;
        int running = 0;
        for (int c = 0; c < nblk; c += BLK) {
            int bb = c + t;
            int pv = (bb < nblk) ? ws[WS_PART + e * NBM + bb] : 0;
            int s = pv;
#pragma unroll
            for (int d = 1; d < 64; d <<= 1) {
                int u = __shfl_up(s, d, 64);
                if (lane >= d) s += u;
            }
            if (lane == 63) wsum[wid] = s;
            __syncthreads();
            int off = 0;
#pragma unroll
            for (int w = 0; w < 4; ++w)
                if (w < wid) off += wsum[w];
            if (bb < nblk) ws[WS_PART + e * NBM + bb] = running + off + (s - pv);
            int tot = wsum[0] + wsum[1] + wsum[2] + wsum[3];
            __syncthreads();
            running += tot;
        }
        if (t == 0) ws[e] = running;
    }
    __threadfence();
    grid.sync();

    // ---- phase C: block 0 wave 0: padded segment offsets ----
    if (b == 0 && t < L_EXP) {
        int cnt = ws[t];
        int pad = ((cnt + SEGPAD - 1) / SEGPAD) * SEGPAD;
        int s = pad;
#pragma unroll
        for (int d = 1; d < L_EXP; d <<= 1) {
            int u = __shfl_up(s, d, 64);
            if (t >= d) s += u;
        }
        ws[16 + t] = s - pad;             // exclusive padded offset
        if (t == L_EXP - 1) ws[32] = s;   // padded total
    }
    __threadfence();
    grid.sync();

    // ---- phase D: scatter (idx still in registers from phase A) ----
    if (t < L_EXP) {
        soff[t] = ws[16 + t] + ws[WS_PART + t * NBM + b];
        lcount[t] = 0;
    }
    __syncthreads();
    {
        int q[4] = {v.x, v.y, v.z, v.w};
#pragma unroll
        for (int m = 0; m < 4; ++m) {
            if (q[m] >= 0) {
                int e = q[m] & 15;
                int r = atomicAdd(&lcount[e], 1);   // LDS only
                ws[WS_PERM + soff[e] + r] = i4 + m;
            }
        }
    }
}

__device__ __forceinline__ float leaky(float a) { return fmaxf(a, NEG * a); }

__device__ __forceinline__ float fdot2(h2 a, h2 b, float c) {
    return __builtin_amdgcn_fdot2(a, b, c, false);
}

__global__ void __launch_bounds__(BLK, 2) k_mlp(
    const int* __restrict__ meta, const float* __restrict__ x,
    const float* __restrict__ b0, const float* __restrict__ b1,
    const float* __restrict__ b2, float* __restrict__ out) {
    __shared__ __align__(16) __half sW0t[C0 * 8];     // [o][c0..7]  256 B
    __shared__ __align__(16) __half sW1t[C1 * C0];    // [o][c0..15] 1 KB
    __shared__ __align__(16) __half sW2t[C2 * C1];    // [o][c0..31] 1 KB
    __shared__ __align__(16) float sB0[C0];
    __shared__ __align__(16) float sB1[C1];
    __shared__ __align__(16) float sB2[C2];

    int start = blockIdx.x * SEGPAD;
    if (start >= meta[32]) return;  // uniform

    int e = 0;
    while (start >= meta[16 + e + 1]) ++e;
    e = __builtin_amdgcn_readfirstlane(e);

    int t = threadIdx.x;
    {
        const int* w0i = (const int*)((const char*)meta + WB_W0T) + e * 64;
        const int* w1i = (const int*)((const char*)meta + WB_W1T) + e * 256;
        const int* w2i = (const int*)((const char*)meta + WB_W2T) + e * 256;
        if (t < 64) reinterpret_cast<int*>(sW0t)[t] = w0i[t];
        reinterpret_cast<int*>(sW1t)[t] = w1i[t];
        reinterpret_cast<int*>(sW2t)[t] = w2i[t];
        if (t >= 128 && t < 128 + C0) sB0[t - 128] = b0[e * C0 + (t - 128)];
        if (t >= 160 && t < 160 + C1) sB1[t - 160] = b1[e * C1 + (t - 160)];
        if (t >= 192 && t < 192 + C2) sB2[t - 192] = b2[e * C2 + (t - 192)];
    }
    __syncthreads();

    int seg = meta[16 + e];
    int cnt = meta[e];
    int j0 = start - seg + t;

    h2  xh[MPT][4];
    int pid[MPT];
    bool act[MPT];
#pragma unroll
    for (int m = 0; m < MPT; ++m) {
        int j = j0 + m * BLK;
        act[m] = (j < cnt);
        int p = meta[WS_PERM + seg + j];   // pad slots: poison ->
        pid[m] = act[m] ? p : 0;           // clamp (no divergent flow)
        const float* xp = x + (size_t)pid[m] * IN0;
        float4 a = *reinterpret_cast<const float4*>(xp);
        float4 b = *reinterpret_cast<const float4*>(xp + 3);
        xh[m][0] = pk(a.x, a.y);
        xh[m][1] = pk(a.z, a.w);
        xh[m][2] = pk(b.y, b.z);
        xh[m][3] = pk(b.w, 0.0f);  // pad c=7 (weight there is 0 too)
    }
    __builtin_amdgcn_sched_barrier(0);

    // ---- Layer 0: 7 -> 16. Per o: one b128 row (4 half2), 4 fdot2/pt ----
    float h0f[MPT][C0];
#pragma unroll
    for (int o = 0; o < C0; ++o) {
        F4H u;
        u.f4 = *reinterpret_cast<const float4*>(&sW0t[o * 8]);
#pragma unroll
        for (int m = 0; m < MPT; ++m) {
            float a = sB0[o];
            a = fdot2(xh[m][0], u.h[0], a);
            a = fdot2(xh[m][1], u.h[1], a);
            a = fdot2(xh[m][2], u.h[2], a);
            a = fdot2(xh[m][3], u.h[3], a);
            h0f[m][o] = leaky(a);
        }
        if (o == 7) __builtin_amdgcn_sched_barrier(0);  // mid-layer fence
    }
    // pack h0 into half2 pairs for layer-1 dot2
    h2 h0h[MPT][8];
#pragma unroll
    for (int m = 0; m < MPT; ++m)
#pragma unroll
        for (int p = 0; p < 8; ++p)
            h0h[m][p] = pk(h0f[m][2 * p], h0f[m][2 * p + 1]);
    __builtin_amdgcn_sched_barrier(0);

    // ---- Layers 1+2 fused; REAL loop, 8 h1-neurons per chunk ----
    float h2a[MPT][C2];
#pragma unroll
    for (int m = 0; m < MPT; ++m)
#pragma unroll
        for (int o = 0; o < C2; ++o) h2a[m][o] = sB2[o];
#pragma unroll 1
    for (int ch = 0; ch < C1 / 8; ++ch) {   // h1 neurons ch*8 .. ch*8+7
        float tvf[MPT][8];
#pragma unroll
        for (int o8 = 0; o8 < 8; ++o8) {
            int o = ch * 8 + o8;
            F4H ua, ub;
            ua.f4 = reinterpret_cast<const float4*>(&sW1t[o * C0])[0];
            ub.f4 = reinterpret_cast<const float4*>(&sW1t[o * C0])[1];
#pragma unroll
            for (int m = 0; m < MPT; ++m) {
                float a = sB1[o];
                a = fdot2(h0h[m][0], ua.h[0], a);
                a = fdot2(h0h[m][1], ua.h[1], a);
                a = fdot2(h0h[m][2], ua.h[2], a);
                a = fdot2(h0h[m][3], ua.h[3], a);
                a = fdot2(h0h[m][4], ub.h[0], a);
                a = fdot2(h0h[m][5], ub.h[1], a);
                a = fdot2(h0h[m][6], ub.h[2], a);
                a = fdot2(h0h[m][7], ub.h[3], a);
                tvf[m][o8] = leaky(a);
            }
        }
        __builtin_amdgcn_sched_barrier(0);
        h2 tvh[MPT][4];
#pragma unroll
        for (int m = 0; m < MPT; ++m)
#pragma unroll
            for (int p = 0; p < 4; ++p)
                tvh[m][p] = pk(tvf[m][2 * p], tvf[m][2 * p + 1]);
#pragma unroll
        for (int o = 0; o < C2; ++o) {
            F4H u;
            u.f4 = *reinterpret_cast<const float4*>(&sW2t[o * C1 + ch * 8]);
#pragma unroll
            for (int m = 0; m < MPT; ++m) {
                float a = h2a[m][o];
                a = fdot2(tvh[m][0], u.h[0], a);
                a = fdot2(tvh[m][1], u.h[1], a);
                a = fdot2(tvh[m][2], u.h[2], a);
                a = fdot2(tvh[m][3], u.h[3], a);
                h2a[m][o] = a;
            }
        }
        __builtin_amdgcn_sched_barrier(0);  // fence at chunk boundary
    }

    // ---- predicated stores ----
#pragma unroll
    for (int m = 0; m < MPT; ++m) {
        if (act[m]) {
            float4* outp = reinterpret_cast<float4*>(out + (size_t)pid[m] * C2);
#pragma unroll
            for (int og = 0; og < C2 / 4; ++og) {
                float4 o;
                o.x = leaky(h2a[m][og * 4 + 0]);
                o.y = leaky(h2a[m][og * 4 + 1]);
                o.z = leaky(h2a[m][og * 4 + 2]);
                o.w = leaky(h2a[m][og * 4 + 3]);
                outp[og] = o;
            }
        }
    }
}

extern "C" void kernel_launch(void* const* d_in, const int* in_sizes, int n_in,
                              void* d_out, int out_size, void* d_ws, size_t ws_size,
                              hipStream_t stream) {
    const float* x  = (const float*)d_in[0];
    const int*  idx = (const int*)d_in[1];
    const float* W0 = (const float*)d_in[2];
    const float* b0 = (const float*)d_in[3];
    const float* W1 = (const float*)d_in[4];
    const float* b1 = (const float*)d_in[5];
    const float* W2 = (const float*)d_in[6];
    const float* b2 = (const float*)d_in[7];
    float* out = (float*)d_out;

    int n = in_sizes[1];  // N
    int* ws = (int*)d_ws;

    int nblk = (n + CHUNK - 1) / CHUNK;   // <= NBM

    void* args[] = {(void*)&idx, (void*)&n, (void*)&nblk, (void*)&ws,
                    (void*)&W0, (void*)&W1, (void*)&W2};
    hipLaunchCooperativeKernel((const void*)k_pre, dim3(nblk), dim3(BLK),
                               args, 0, stream);

    int mblk = (n + L_EXP * (SEGPAD - 1) + SEGPAD - 1) / SEGPAD;
    k_mlp<<<mblk, BLK, 0, stream>>>(ws, x, b0, b1, b2, out);
}

// Round 3
// 127.843 us; speedup vs baseline: 2.8040x; 2.8040x over previous
//
#include <hip/hip_runtime.h>
#include <hip/hip_fp16.h>

// Per-point expert-indexed MLP: h = LeakyReLU(h @ W[idx] + b[idx]) x3.
//
// R13: SINGLE fused kernel. All 16 experts' fp16 weights (36 KB) staged in
// LDS per block with expert-INNERMOST interleave [o][q][e] (16 B granules):
// 64 lanes reading 16 distinct expert rows tile 256 B exactly -> 2 words/bank
// -> conflict-free (2-way aliasing is free per m136). Points processed in
// NATURAL order: no hist/scan/scatter, no perm, no workspace, no gather.
// Removes 3 dispatches + all inter-dispatch gaps + the cooperative-sync
// disaster (R12: grid.sync spin = 237us, VALUBusy 0.13%).
//
// Cost model: per wave of 64 pts: 144 ds_read_b128 (16 L0 + 64 L1 + 64 L2)
// ~12cyc each + 48 scalar bias reads -> LDS pipe ~22us; VALU ~650 inst/pt
// ~4us; HBM 48 MB coalesced ~8us. Expect ~22-27us kernel.
// L0 bias folded into the c=7 pad slot (x7 = 1.0, w7 = b0[o]) - free.

#define L_EXP 16
#define IN0   7
#define C0    16
#define C1    32
#define C2    16
#define NEG   0.2f
#define BLK   256
#define MPT   2           // points per thread (sequential; halves staging)

typedef _Float16 h2 __attribute__((ext_vector_type(2)));
union F4H { float4 f4; h2 h[4]; };

__device__ __forceinline__ h2 pk(float a, float b) {
    return __builtin_bit_cast(h2, __builtin_amdgcn_cvt_pkrtz(a, b));
}
__device__ __forceinline__ float leaky(float a) { return fmaxf(a, NEG * a); }
__device__ __forceinline__ float fdot2(h2 a, h2 b, float c) {
    return __builtin_amdgcn_fdot2(a, b, c, false);
}

__global__ void __launch_bounds__(BLK, 4) k_fused(
    const float* __restrict__ x, const int* __restrict__ idx,
    const float* __restrict__ W0, const float* __restrict__ b0,
    const float* __restrict__ W1, const float* __restrict__ b1,
    const float* __restrict__ W2, const float* __restrict__ b2,
    float* __restrict__ out, int n) {
    // expert-innermost fp16 weight tiles; 16 B per (row, expert)
    __shared__ __align__(16) __half sW0[C0 * L_EXP * 8];      // [o][e][8]  4 KB (c7 = bias0)
    __shared__ __align__(16) __half sW1[C1 * 2 * L_EXP * 8];  // [o][q][e][8] 16 KB
    __shared__ __align__(16) __half sW2[C2 * 4 * L_EXP * 8];  // [o][q][e][8] 16 KB
    __shared__ float sB1[C1 * L_EXP];                          // [o][e] 2 KB
    __shared__ float sB2[C2 * L_EXP];                          // [o][e] 1 KB

    int t = threadIdx.x;

    // ---- stage all experts' weights (once per block) ----
    {   // W0: 256 rows of 8 halves; row k: o=k>>4, e=k&15; c=0..6 + bias slot
        int o = t >> 4, e = t & 15;
        float v0 = W0[e * (IN0 * C0) + 0 * C0 + o];
        float v1 = W0[e * (IN0 * C0) + 1 * C0 + o];
        float v2 = W0[e * (IN0 * C0) + 2 * C0 + o];
        float v3 = W0[e * (IN0 * C0) + 3 * C0 + o];
        float v4 = W0[e * (IN0 * C0) + 4 * C0 + o];
        float v5 = W0[e * (IN0 * C0) + 5 * C0 + o];
        float v6 = W0[e * (IN0 * C0) + 6 * C0 + o];
        float v7 = b0[e * C0 + o];           // bias via x7=1.0
        F4H u;
        u.h[0] = pk(v0, v1); u.h[1] = pk(v2, v3);
        u.h[2] = pk(v4, v5); u.h[3] = pk(v6, v7);
        reinterpret_cast<float4*>(sW0)[t] = u.f4;
    }
#pragma unroll
    for (int rr = 0; rr < 4; ++rr) {  // W1: 1024 rows; row r=(o*2+q)*16+e
        int r = rr * BLK + t;
        int o = r >> 5, q = (r >> 4) & 1, e = r & 15;
        const float* wp = W1 + e * (C0 * C1) + (q * 8) * C1 + o;
        F4H u;
#pragma unroll
        for (int j = 0; j < 4; ++j)
            u.h[j] = pk(wp[(2 * j) * C1], wp[(2 * j + 1) * C1]);
        reinterpret_cast<float4*>(sW1)[r] = u.f4;
    }
#pragma unroll
    for (int rr = 0; rr < 4; ++rr) {  // W2: 1024 rows; row r=(o*4+q)*16+e
        int r = rr * BLK + t;
        int o = r >> 6, q = (r >> 4) & 3, e = r & 15;
        const float* wp = W2 + e * (C1 * C2) + (q * 8) * C2 + o;
        F4H u;
#pragma unroll
        for (int j = 0; j < 4; ++j)
            u.h[j] = pk(wp[(2 * j) * C2], wp[(2 * j + 1) * C2]);
        reinterpret_cast<float4*>(sW2)[r] = u.f4;
    }
    {   // biases [o][e]
        int o = t >> 4, e = t & 15;
        sB1[t] = b1[e * C1 + o];                       // o 0..15
        int r2 = t + 256; int o2 = r2 >> 4, e2 = r2 & 15;
        sB1[r2] = b1[e2 * C1 + o2];                    // o 16..31
        sB2[t] = b2[e * C2 + o];
    }
    __syncthreads();

    int base = blockIdx.x * (BLK * MPT);
#pragma unroll 1
    for (int m = 0; m < MPT; ++m) {
        int i = base + m * BLK + t;
        bool act = (i < n);
        int ii = act ? i : (n - 1);
        int e = idx[ii] & 15;

        const float* xp = x + (size_t)ii * IN0;
        float x0 = xp[0], x1 = xp[1], x2 = xp[2], x3 = xp[3];
        float x4 = xp[4], x5 = xp[5], x6 = xp[6];
        h2 xh0 = pk(x0, x1), xh1 = pk(x2, x3);
        h2 xh2 = pk(x4, x5), xh3 = pk(x6, 1.0f);  // 1.0 activates bias slot

        const char* w0p = (const char*)sW0 + e * 16;
        const char* w1p = (const char*)sW1 + e * 16;
        const char* w2p = (const char*)sW2 + e * 16;

        // ---- Layer 0: 7(+bias) -> 16, pairwise to keep live ranges small ----
        h2 h0h[8];
#pragma unroll
        for (int op = 0; op < 8; ++op) {
            F4H ua, ub;
            ua.f4 = *reinterpret_cast<const float4*>(w0p + (2 * op) * 256);
            ub.f4 = *reinterpret_cast<const float4*>(w0p + (2 * op + 1) * 256);
            float a0 = 0.f, a1 = 0.f;
            a0 = fdot2(xh0, ua.h[0], a0); a1 = fdot2(xh0, ub.h[0], a1);
            a0 = fdot2(xh1, ua.h[1], a0); a1 = fdot2(xh1, ub.h[1], a1);
            a0 = fdot2(xh2, ua.h[2], a0); a1 = fdot2(xh2, ub.h[2], a1);
            a0 = fdot2(xh3, ua.h[3], a0); a1 = fdot2(xh3, ub.h[3], a1);
            h0h[op] = pk(leaky(a0), leaky(a1));
        }

        // ---- Layer 1: 16 -> 32, pairwise ----
        h2 tvh[16];
#pragma unroll
        for (int op = 0; op < 16; ++op) {
            F4H ua, ub, uc, ud;   // rows for outputs 2op, 2op+1 (2 x 32 B)
            ua.f4 = *reinterpret_cast<const float4*>(w1p + (4 * op + 0) * 256);
            ub.f4 = *reinterpret_cast<const float4*>(w1p + (4 * op + 1) * 256);
            uc.f4 = *reinterpret_cast<const float4*>(w1p + (4 * op + 2) * 256);
            ud.f4 = *reinterpret_cast<const float4*>(w1p + (4 * op + 3) * 256);
            float a0 = sB1[(2 * op) * 16 + e];
            float a1 = sB1[(2 * op + 1) * 16 + e];
#pragma unroll
            for (int p = 0; p < 4; ++p) {
                a0 = fdot2(h0h[p], ua.h[p], a0);
                a1 = fdot2(h0h[p], uc.h[p], a1);
            }
#pragma unroll
            for (int p = 0; p < 4; ++p) {
                a0 = fdot2(h0h[4 + p], ub.h[p], a0);
                a1 = fdot2(h0h[4 + p], ud.h[p], a1);
            }
            tvh[op] = pk(leaky(a0), leaky(a1));
        }

        // ---- Layer 2: 32 -> 16 ----
        float4 ov[4];
#pragma unroll
        for (int o = 0; o < C2; ++o) {
            F4H ua, ub, uc, ud;   // 64 B row for output o
            ua.f4 = *reinterpret_cast<const float4*>(w2p + (4 * o + 0) * 256);
            ub.f4 = *reinterpret_cast<const float4*>(w2p + (4 * o + 1) * 256);
            uc.f4 = *reinterpret_cast<const float4*>(w2p + (4 * o + 2) * 256);
            ud.f4 = *reinterpret_cast<const float4*>(w2p + (4 * o + 3) * 256);
            float a = sB2[o * 16 + e];
#pragma unroll
            for (int p = 0; p < 4; ++p) a = fdot2(tvh[p],      ua.h[p], a);
#pragma unroll
            for (int p = 0; p < 4; ++p) a = fdot2(tvh[4 + p],  ub.h[p], a);
#pragma unroll
            for (int p = 0; p < 4; ++p) a = fdot2(tvh[8 + p],  uc.h[p], a);
#pragma unroll
            for (int p = 0; p < 4; ++p) a = fdot2(tvh[12 + p], ud.h[p], a);
            float r = leaky(a);
            if ((o & 3) == 0) ov[o >> 2].x = r;
            else if ((o & 3) == 1) ov[o >> 2].y = r;
            else if ((o & 3) == 2) ov[o >> 2].z = r;
            else ov[o >> 2].w = r;
        }

        if (act) {
            float4* op = reinterpret_cast<float4*>(out + (size_t)i * C2);
            op[0] = ov[0]; op[1] = ov[1]; op[2] = ov[2]; op[3] = ov[3];
        }
    }
}

extern "C" void kernel_launch(void* const* d_in, const int* in_sizes, int n_in,
                              void* d_out, int out_size, void* d_ws, size_t ws_size,
                              hipStream_t stream) {
    const float* x  = (const float*)d_in[0];
    const int*  idx = (const int*)d_in[1];
    const float* W0 = (const float*)d_in[2];
    const float* b0 = (const float*)d_in[3];
    const float* W1 = (const float*)d_in[4];
    const float* b1 = (const float*)d_in[5];
    const float* W2 = (const float*)d_in[6];
    const float* b2 = (const float*)d_in[7];
    float* out = (float*)d_out;

    int n = in_sizes[1];  // N
    int blocks = (n + BLK * MPT - 1) / (BLK * MPT);
    k_fused<<<blocks, BLK, 0, stream>>>(x, idx, W0, b0, W1, b1, W2, b2, out, n);
}